// Round 5
// baseline (509.216 us; speedup 1.0000x reference)
//
#include <hip/hip_runtime.h>
#include <cstdint>
#include <cstddef>

#define B_ 4
#define C_ 512
#define T_ 2048
#define S_ 2048
#define EPSF 1e-5f

typedef __bf16 bf16;
typedef __attribute__((ext_vector_type(8))) __bf16 bf16x8;
typedef __attribute__((ext_vector_type(4))) float f32x4;

__device__ __forceinline__ bf16 f2b(float f){ return (bf16)f; }
__device__ __forceinline__ float b2f(bf16 h){ return (float)h; }

__device__ __forceinline__ void gl_lds16(const void* g, void* l){
  __builtin_amdgcn_global_load_lds((__attribute__((address_space(1))) void*)(g),
                                   (__attribute__((address_space(3))) void*)(l), 16, 0, 0);
}

__device__ __forceinline__ float wave_sum(float v){
#pragma unroll
  for (int o = 32; o; o >>= 1) v += __shfl_xor(v, o, 64);
  return v;
}
__device__ __forceinline__ float wave_max(float v){
#pragma unroll
  for (int o = 32; o; o >>= 1) v = fmaxf(v, __shfl_xor(v, o, 64));
  return v;
}

// ---------------------------------------------------------------------------
// NT GEMM: C[m,n] = sum_k A[m,k]*B[n,k], both operands k-contiguous (bf16),
// fp32 MFMA accum. Tile 128 x (TNW*32), BK=64, 256 threads (2x2 waves).
// z-batched: A offset (z/zdivA)*sA, B offset (z%zmodB)*sB, C offset z*sC.
// EPI 0: bf16 store (acc*scale + cbias[n])
// EPI 2: f32 store relu(acc*rs[m]+rsh[m]) + fused per-row sum/sum^2 atomics
// EPI 3: PV: ones-MFMA row sums l in-register; per-column sum/sum^2 over m of
//        acc/l[row] -> atomics into osum/osum2; c==0 blocks store l to Cout.
//        Uses XCD-pinned 1-D grid decode (z=id&7, c-block fastest).
// EPI 5: bf16 store exp(acc)   (unnormalized softmax numerator)
// ---------------------------------------------------------------------------
template<int EPI, int TNW>
__global__ void __launch_bounds__(256) gemm_nt(
    const bf16* __restrict__ A, const bf16* __restrict__ Bm, void* __restrict__ Cout,
    int K, int lda, int ldb, int ldc,
    long long sA, long long sB, long long sC, long long sCb,
    int zdivA, int zmodB, float scale,
    const float* __restrict__ rs, const float* __restrict__ rsh,
    const float* __restrict__ cbias,
    float* __restrict__ osum, float* __restrict__ osum2, long long sRs)
{
  constexpr int TN = TNW*32;
  __shared__ alignas(16) bf16 lA[128*64];
  __shared__ alignas(16) bf16 lB[TN*64];
  __shared__ float l_sh[128];
  const int tid = threadIdx.x;
  int z, m0, n0;
  if (EPI == 3) {         // XCD-pinned swizzle: z = id&7, c-block fastest
    const int id = blockIdx.x;
    z = id & 7;
    const int r = id >> 3;
    n0 = (r & 3) * TN;    // C_/TN must be 4 (TNW=4)
    m0 = (r >> 2) * 128;
  } else {
    z = blockIdx.z; m0 = blockIdx.y*128; n0 = blockIdx.x*TN;
  }
  const bf16* Ab = A + (long long)(z / zdivA) * sA;
  const bf16* Bb = Bm + (long long)(z % zmodB) * sB;
  const int lane = tid & 63, wvi = tid >> 6;
  const int wm = wvi >> 1, wn = wvi & 1;

  f32x4 acc[4][TNW] = {};
  f32x4 accL[4] = {};                       // EPI==3: row sums via ones-MFMA
  bf16x8 vone;
#pragma unroll
  for (int j = 0; j < 8; ++j) vone[j] = f2b(1.f);

  // loader: thread stages one 16B chunk/iter; XOR-swizzle k-chunk by (row&7)
  const int lrow = tid >> 3;
  const int lcol = ((tid ^ lrow) & 7) * 8;
  const bf16* pa = Ab + (long long)(m0 + lrow)*lda + lcol;
  const bf16* pb = Bb + (long long)(n0 + lrow)*ldb + lcol;
  char* sa = (char*)lA + tid*16;
  char* sb = (char*)lB + tid*16;

  for (int k0 = 0; k0 < K; k0 += 64) {
#pragma unroll
    for (int it = 0; it < 4; ++it)
      gl_lds16(pa + (long long)it*32*lda + k0, sa + it*4096);
#pragma unroll
    for (int it = 0; it < TNW; ++it)
      gl_lds16(pb + (long long)it*32*ldb + k0, sb + it*4096);
    __syncthreads();
#pragma unroll
    for (int ks = 0; ks < 2; ++ks) {
      const int kq = ks*4 + (lane >> 4);
      bf16x8 af[4], bfr[TNW];
#pragma unroll
      for (int mt = 0; mt < 4; ++mt) {
        int r = wm*64 + mt*16 + (lane & 15);
        af[mt] = *(const bf16x8*)&lA[r*64 + ((kq ^ (r & 7))*8)];
      }
#pragma unroll
      for (int nt = 0; nt < TNW; ++nt) {
        int r = wn*(TNW*16) + nt*16 + (lane & 15);
        bfr[nt] = *(const bf16x8*)&lB[r*64 + ((kq ^ (r & 7))*8)];
      }
#pragma unroll
      for (int mt = 0; mt < 4; ++mt)
#pragma unroll
        for (int nt = 0; nt < TNW; ++nt)
          acc[mt][nt] = __builtin_amdgcn_mfma_f32_16x16x32_bf16(af[mt], bfr[nt], acc[mt][nt], 0, 0, 0);
      if (EPI == 3 && wn == 0) {
#pragma unroll
        for (int mt = 0; mt < 4; ++mt)
          accL[mt] = __builtin_amdgcn_mfma_f32_16x16x32_bf16(af[mt], vone, accL[mt], 0, 0, 0);
      }
    }
    __syncthreads();
  }

  if (EPI == 3) {
    // publish l (row sums) to LDS, then normalize-and-reduce columns.
    if (wn == 0 && (lane & 15) == 0) {
#pragma unroll
      for (int mt = 0; mt < 4; ++mt)
#pragma unroll
        for (int i = 0; i < 4; ++i)
          l_sh[wm*64 + mt*16 + (lane >> 4)*4 + i] = accL[mt][i];
    }
    __syncthreads();
    if (n0 == 0 && tid < 128)
      ((float*)Cout)[(long long)z*sC + m0 + tid] = l_sh[tid];
    float linv[4][4];
#pragma unroll
    for (int mt = 0; mt < 4; ++mt)
#pragma unroll
      for (int i = 0; i < 4; ++i)
        linv[mt][i] = 1.f / l_sh[wm*64 + mt*16 + (lane >> 4)*4 + i];
    float* red1 = (float*)lA;                 // [4][TNW][16] aliased scratch
    float* red2 = red1 + 4*TNW*16;
    float s1[TNW], s2[TNW];
#pragma unroll
    for (int nt = 0; nt < TNW; ++nt) {
      s1[nt] = 0.f; s2[nt] = 0.f;
#pragma unroll
      for (int mt = 0; mt < 4; ++mt)
#pragma unroll
        for (int i = 0; i < 4; ++i) {
          float v = acc[mt][nt][i] * linv[mt][i];
          s1[nt] += v; s2[nt] += v*v;
        }
      s1[nt] += __shfl_xor(s1[nt], 16, 64);
      s1[nt] += __shfl_xor(s1[nt], 32, 64);
      s2[nt] += __shfl_xor(s2[nt], 16, 64);
      s2[nt] += __shfl_xor(s2[nt], 32, 64);
    }
    if (lane < 16) {
#pragma unroll
      for (int nt = 0; nt < TNW; ++nt) {
        red1[(wvi*TNW + nt)*16 + lane] = s1[nt];
        red2[(wvi*TNW + nt)*16 + lane] = s2[nt];
      }
    }
    __syncthreads();
    if (tid < 2*TN) {
      const int which = tid >= TN;
      const int col = tid - which*TN;
      const int wn2 = col / (TNW*16), rem = col % (TNW*16);
      const float* rr = which ? red2 : red1;
      float v = rr[wn2*(TNW*16) + rem] + rr[(2+wn2)*(TNW*16) + rem];
      float* dst = which ? osum2 : osum;
      atomicAdd(&dst[sCb*z + n0 + col], v);
    }
    return;
  }

  const int cr = (lane >> 4)*4, cc = lane & 15;
#pragma unroll
  for (int mt = 0; mt < 4; ++mt) {
#pragma unroll
    for (int i = 0; i < 4; ++i) {
      const int mm = m0 + wm*64 + mt*16 + cr + i;
      float rsum = 0.f, rsum2 = 0.f;
#pragma unroll
      for (int nt = 0; nt < TNW; ++nt) {
        const int nn = n0 + wn*(TNW*16) + nt*16 + cc;
        float v = acc[mt][nt][i];
        const long long co = sC*z + (long long)mm*ldc + nn;
        if (EPI == 0) {
          v *= scale;
          if (cbias) v += cbias[sCb*z + nn];
          ((bf16*)Cout)[co] = f2b(v);
        } else if (EPI == 2) {
          v = fmaxf(v*rs[mm] + rsh[mm], 0.f);
          ((float*)Cout)[co] = v;
          rsum += v; rsum2 += v*v;
        } else if (EPI == 5) {
          ((bf16*)Cout)[co] = f2b(__expf(v));
        }
      }
      if (EPI == 2) {
        rsum += __shfl_xor(rsum, 1, 64); rsum += __shfl_xor(rsum, 2, 64);
        rsum += __shfl_xor(rsum, 4, 64); rsum += __shfl_xor(rsum, 8, 64);
        rsum2 += __shfl_xor(rsum2, 1, 64); rsum2 += __shfl_xor(rsum2, 2, 64);
        rsum2 += __shfl_xor(rsum2, 4, 64); rsum2 += __shfl_xor(rsum2, 8, 64);
        if (cc == 0) {
          atomicAdd(&osum[(long long)z*sRs + mm], rsum);
          atomicAdd(&osum2[(long long)z*sRs + mm], rsum2);
        }
      }
    }
  }
}

// ---- fused input stats: raw col sums (over C, per t) direct; raw row sums
//      (over T, per c) via wave-reduce + atomics. src z<B, trg z>=B. ---------
__global__ void __launch_bounds__(256) stats_k(const float* __restrict__ src,
    const float* __restrict__ trg, float* __restrict__ tsum, float* __restrict__ tsum2,
    float* __restrict__ rsum, float* __restrict__ rsum2)
{
  __shared__ float r1[4][64], r2[4][64];
  const int z = blockIdx.y, t0 = blockIdx.x*64;
  const float* X = (z < B_) ? src : trg;
  const int b = z & (B_-1);
  const int tl = threadIdx.x & 63, cg = threadIdx.x >> 6;
  float s1 = 0.f, s2 = 0.f;
  for (int c = cg; c < C_; c += 4) {
    float v = X[((long long)b*C_ + c)*T_ + t0 + tl];
    s1 += v; s2 += v*v;
    float a  = wave_sum(v);
    float a2 = wave_sum(v*v);
    if (tl == 0) {
      atomicAdd(&rsum[z*C_ + c], a);
      atomicAdd(&rsum2[z*C_ + c], a2);
    }
  }
  r1[cg][tl] = s1; r2[cg][tl] = s2;
  __syncthreads();
  if (cg == 0) {
    s1 = r1[0][tl]+r1[1][tl]+r1[2][tl]+r1[3][tl];
    s2 = r2[0][tl]+r2[1][tl]+r2[2][tl]+r2[3][tl];
    tsum[z*T_ + t0 + tl] = s1;
    tsum2[z*T_ + t0 + tl] = s2;
  }
}

// ---- transpose [C,T]->[T,C] + tinorm & inorm bf16 (stats finalized inline) -
__global__ void __launch_bounds__(256) transform_k(const float* __restrict__ src,
    const float* __restrict__ trg,
    const float* __restrict__ tsum, const float* __restrict__ tsum2,
    const float* __restrict__ rsum, const float* __restrict__ rsum2,
    bf16* __restrict__ NSt, bf16* __restrict__ NSc,
    bf16* __restrict__ NTt, bf16* __restrict__ NTc, bf16* __restrict__ TTr)
{
  __shared__ float tile[32][33];
  const int z = blockIdx.z, t0 = blockIdx.x*32, c0 = blockIdx.y*32;
  const int is_t = z >= B_, b = z & (B_-1);
  const float* X = is_t ? trg : src;
  const int tx = threadIdx.x, ty = threadIdx.y;
#pragma unroll
  for (int r = 0; r < 4; ++r) {
    int ci = ty + r*8;
    tile[ci][tx] = X[((long long)b*C_ + c0 + ci)*T_ + t0 + tx];
  }
  __syncthreads();
#pragma unroll
  for (int r = 0; r < 4; ++r) {
    int tj = ty + r*8, ci = tx;
    float v = tile[ci][tj];
    int gt = t0 + tj, gc = c0 + ci;
    float ts1 = tsum[z*T_ + gt], ts2 = tsum2[z*T_ + gt];
    float tm = ts1 * (1.f/C_);
    float tsd = sqrtf(fmaxf((ts2 - ts1*tm) * (1.f/(C_-1)), 0.f)) + EPSF;
    float rs1 = rsum[z*C_ + gc], rs2 = rsum2[z*C_ + gc];
    float im = rs1 * (1.f/T_);
    float isd = sqrtf(fmaxf((rs2 - rs1*im) * (1.f/(T_-1)), 0.f)) + EPSF;
    float a = (v - tm) / tsd;
    float d = (v - im) / isd;
    long long o = ((long long)b*T_ + gt)*C_ + gc;
    if (is_t) { NTt[o] = f2b(a); NTc[o] = f2b(d); TTr[o] = f2b(v); }
    else      { NSt[o] = f2b(a); NSc[o] = f2b(d); }
  }
}

// ---- fp32 row softmax (SAP) ------------------------------------------------
__global__ void __launch_bounds__(256) softmax_row_k(const float* __restrict__ X, float* __restrict__ O)
{
  __shared__ float red[4];
  const long long row = blockIdx.x;
  const float* x = X + row*T_ + threadIdx.x*8;
  float v[8];
  f32x4 a0 = *(const f32x4*)x;
  f32x4 a1 = *(const f32x4*)(x + 4);
#pragma unroll
  for (int j = 0; j < 4; ++j){ v[j] = a0[j]; v[4+j] = a1[j]; }
  float m = -3.4e38f;
#pragma unroll
  for (int j = 0; j < 8; ++j) m = fmaxf(m, v[j]);
  m = wave_max(m);
  const int lane = threadIdx.x & 63, w = threadIdx.x >> 6;
  if (!lane) red[w] = m;
  __syncthreads();
  m = fmaxf(fmaxf(red[0], red[1]), fmaxf(red[2], red[3]));
  __syncthreads();
  float s = 0.f;
#pragma unroll
  for (int j = 0; j < 8; ++j){ v[j] = __expf(v[j] - m); s += v[j]; }
  s = wave_sum(s);
  if (!lane) red[w] = s;
  __syncthreads();
  s = red[0]+red[1]+red[2]+red[3];
  const float inv = 1.f/s;
  float* o = O + row*T_ + threadIdx.x*8;
#pragma unroll
  for (int j = 0; j < 8; ++j) o[j] = v[j]*inv;
}

// ---- normalized column sums of P' over s (chunked, atomic), z in [0,2B) ----
__global__ void __launch_bounds__(256) colsum_k(const bf16* __restrict__ P,
    const float* __restrict__ l, float* __restrict__ cs)
{
  __shared__ float linv[256];
  const int t = blockIdx.x*256 + threadIdx.x;
  const int z = blockIdx.z;
  const long long s0 = (long long)blockIdx.y*256;
  linv[threadIdx.x] = 1.f / l[(long long)z*S_ + s0 + threadIdx.x];
  __syncthreads();
  const bf16* p = P + ((long long)z*S_ + s0)*T_ + t;
  float a = 0.f;
  for (int s = 0; s < 256; ++s) a += b2f(p[(long long)s*T_]) * linv[s];
  atomicAdd(&cs[z*T_ + t], a);
}

// ---- vv-GEMV + finalize mean_c / std_c, z in [0,2B) ------------------------
__global__ void __launch_bounds__(256) vv_fin_k(const float* __restrict__ cs,
    const bf16* __restrict__ VT, const float* __restrict__ msum,
    const float* __restrict__ m2sum, float* __restrict__ meanc, float* __restrict__ stdc)
{
  __shared__ float r1[4];
  const int c = blockIdx.x, z = blockIdx.y;
  const bf16* vr = VT + ((long long)z*C_ + c)*T_;
  const float* w = cs + z*T_;
  float a = 0.f;
  for (int t = threadIdx.x; t < T_; t += 256){ float v = b2f(vr[t]); a += w[t]*v*v; }
  a = wave_sum(a);
  const int lane = threadIdx.x & 63, wq = threadIdx.x >> 6;
  if (!lane) r1[wq] = a;
  __syncthreads();
  if (threadIdx.x == 0){
    a = r1[0]+r1[1]+r1[2]+r1[3];
    const int idx = z*C_ + c;
    meanc[idx] = msum[idx] * (1.f/S_);
    float var = (a - m2sum[idx]) * (1.f/S_);
    stdc[idx] = sqrtf(fmaxf(var, 0.f));
  }
}

// ---- fold adaptive-norm epilogue + concat into conv1 weights ---------------
__global__ void __launch_bounds__(256) weff_k(const float* __restrict__ w1,
    const float* __restrict__ b1, const float* __restrict__ sdt, const float* __restrict__ sdc,
    const float* __restrict__ mct, const float* __restrict__ mcc,
    bf16* __restrict__ Weff, float* __restrict__ beff)
{
  __shared__ float r1[4];
  const int o = blockIdx.x, b = blockIdx.y;
  float accb = 0.f;
  for (int c = threadIdx.x; c < C_; c += 256) {
    float wa = w1[o*2*C_ + c], wb = w1[o*2*C_ + C_ + c];
    Weff[((long long)(b*C_ + o))*C_ + c] = f2b(wa*sdt[b*C_+c] + wb*sdc[b*C_+c]);
    accb += wa*mct[b*C_+c] + wb*mcc[b*C_+c];
  }
  accb = wave_sum(accb);
  const int lane = threadIdx.x & 63, w = threadIdx.x >> 6;
  if (!lane) r1[w] = accb;
  __syncthreads();
  if (threadIdx.x == 0) beff[b*C_ + o] = b1[o] + r1[0]+r1[1]+r1[2]+r1[3];
}

// ---- merged prep: cast6 | w2r+BN | x1p pad | zero accumulators -------------
__global__ void __launch_bounds__(256) prep_k(
    const float* __restrict__ a0, const float* __restrict__ a1,
    const float* __restrict__ a2, const float* __restrict__ a3,
    const float* __restrict__ a4, const float* __restrict__ a5,
    bf16* __restrict__ WQb,
    const float* __restrict__ w2, const float* __restrict__ g,
    const float* __restrict__ be, const float* __restrict__ mu,
    const float* __restrict__ va, bf16* __restrict__ W2r,
    float* __restrict__ bnsc, float* __restrict__ bnsh,
    bf16* __restrict__ x1p, float* __restrict__ zbase)
{
  const int bid = blockIdx.x, tid = threadIdx.x;
  if (bid < 6144) {                       // cast 6 proj weights (qsc folded)
    const int i = bid*256 + tid;
    const int slot = i >> 18;
    const float* srcs[6] = {a0,a1,a2,a3,a4,a5};
    const float sc = (slot < 2) ? 0.044194173824159216f : 1.f;
    WQb[i] = f2b(srcs[slot][i & 262143] * sc);
  } else if (bid < 6656) {                // conv2 weight reorder + BN consts
    const int o = bid - 6144;
    for (int c = tid; c < C_; c += 256)
#pragma unroll
      for (int dt = 0; dt < 3; ++dt)
        W2r[(long long)o*3*C_ + dt*C_ + c] = f2b(w2[((long long)o*C_ + c)*3 + dt]);
    if (tid == 0) {
      float s = g[o] * rsqrtf(va[o] + EPSF);
      bnsc[o] = s;
      bnsh[o] = be[o] - mu[o]*s;
    }
  } else if (bid < 6672) {                // zero-pad halo rows of x1p
    const int i = (bid - 6656)*256 + tid;
    const int b = i >> 10, rem = i & 1023;
    const long long row = (rem >> 9) ? (T_+1) : 0;
    const int c = rem & (C_-1);
    x1p[((long long)b*(T_+2) + row)*C_ + c] = f2b(0.f);
  } else {                                // zero the accumulator region
    zbase[(bid - 6672)*256 + tid] = 0.f;
  }
}

// ---- SAP: logits (means for z<B, stds for z>=B) ----------------------------
__global__ void __launch_bounds__(256) sap_logit_k(const float* __restrict__ means,
    const float* __restrict__ stds, const float* __restrict__ mw, const float* __restrict__ sw,
    const float* __restrict__ mb, const float* __restrict__ sb, float* __restrict__ out)
{
  const int n = blockIdx.x*4 + (threadIdx.x >> 6);
  const int z = blockIdx.y;
  const int sel = z >= B_, b = z & (B_-1);
  const float* x = sel ? stds : means;
  const float* w = sel ? sw : mw;
  const int lane = threadIdx.x & 63;
  const float* p = x + ((long long)b*S_ + n)*C_;
  float a = 0.f;
  for (int c = lane; c < C_; c += 64) a += p[c]*w[c];
  a = wave_sum(a);
  if (!lane) out[z*S_ + n] = a + (sel ? sb[0] : mb[0]);
}

// ---- SAP: weighted sum over n (chunked, atomic), z in [0,2B) ---------------
__global__ void __launch_bounds__(256) sap_wsum_k(const float* __restrict__ means,
    const float* __restrict__ stds, const float* __restrict__ a, float* __restrict__ out)
{
  const int c = blockIdx.x*256 + threadIdx.x;
  const int z = blockIdx.z;
  const int sel = z >= B_, b = z & (B_-1);
  const float* x = sel ? stds : means;
  const long long n0 = (long long)blockIdx.y*256;
  const float* p = x + ((long long)b*S_ + n0)*C_ + c;
  const float* aw = a + z*S_ + n0;
  float acc = 0.f;
  for (int n = 0; n < 256; ++n) acc += p[(long long)n*C_] * aw[n];
  atomicAdd(&out[z*C_ + c], acc);
}

// ---- final: inorm(y)*sap_std + sap_mean, stats from raw sums ---------------
__global__ void __launch_bounds__(256) final_k(const float* __restrict__ y,
    const float* __restrict__ ysum, const float* __restrict__ y2sum,
    const float* __restrict__ sapms, float* __restrict__ out)
{
  const long long i = (long long)(blockIdx.x*256 + threadIdx.x) * 4;
  const long long r = i >> 11;
  const float s1 = ysum[r], s2 = y2sum[r];
  const float m = s1 * (1.f/T_);
  const float var = (s2 - s1*m) * (1.f/(T_-1));
  const float inv = 1.f/(sqrtf(fmaxf(var, 0.f)) + EPSF);
  const float mn = sapms[r], sd = sapms[B_*C_ + r];
  const f32x4 v = *(const f32x4*)(y + i);
  f32x4 o;
#pragma unroll
  for (int j = 0; j < 4; ++j) o[j] = (v[j] - m)*inv*sd + mn;
  *(f32x4*)(out + i) = o;
}

// ---------------------------------------------------------------------------
extern "C" void kernel_launch(void* const* d_in, const int* in_sizes, int n_in,
                              void* d_out, int out_size, void* d_ws, size_t ws_size,
                              hipStream_t stream)
{
  (void)in_sizes; (void)n_in; (void)out_size; (void)ws_size;
  const float* src    = (const float*)d_in[0];
  const float* trg    = (const float*)d_in[1];
  const float* means  = (const float*)d_in[2];
  const float* stds   = (const float*)d_in[3];
  const float* conv1w = (const float*)d_in[10];
  const float* conv1b = (const float*)d_in[11];
  const float* conv2w = (const float*)d_in[12];
  const float* bn_g   = (const float*)d_in[13];
  const float* bn_b   = (const float*)d_in[14];
  const float* bn_m   = (const float*)d_in[15];
  const float* bn_v   = (const float*)d_in[16];
  const float* msap_w = (const float*)d_in[17];
  const float* msap_b = (const float*)d_in[18];
  const float* ssap_w = (const float*)d_in[19];
  const float* ssap_b = (const float*)d_in[20];

  const long long BTC = (long long)B_*T_*C_;   // 4194304 elems

  char* p = (char*)d_ws;
  auto take = [&](size_t n)->char*{ char* r = p; p += (n + 255) & ~(size_t)255; return r; };

  // Phase convention: p=0 -> CAN (inorm), p=1 -> TAN (tinorm); z = p*B + b.
  bf16* NSc = (bf16*)take(BTC*2);                          // 8 MB
  bf16* P2  = (bf16*)take((size_t)2*B_*S_*T_*2);           // 64 MB (exp logits)
  bf16* NSt = P2;                                          // aliases (dead
  bf16* NTc = P2 + BTC;                                    //  before QK gemm
  bf16* NTt = P2 + 2*BTC;                                  //  writes P2)
  bf16* TTr = P2 + 3*BTC;
  bf16* QK4 = (bf16*)take((size_t)4*BTC*2);                // 32 MB [Qc,Qt,Kc,Kt]
  bf16* VT2 = (bf16*)take((size_t)2*BTC*2);                // 16 MB [2][B][C][T]
  bf16* WQb = (bf16*)take((size_t)6*C_*C_*2);
  bf16* Weff= (bf16*)take((size_t)B_*C_*C_*2);
  bf16* W2r = (bf16*)take((size_t)C_*3*C_*2);
  bf16* x1p = (bf16*)take((size_t)B_*(T_+2)*C_*2);
  float* y  = (float*)take((size_t)B_*C_*T_*4);            // 16 MB
  // contiguous zero region (prep_k part 3): 57344 floats = 224 blocks
  float* colsum = (float*)take(2*B_*T_*4);                 // 16384 f
  float* msum   = (float*)take(2*B_*C_*4);                 // 4096
  float* m2sum  = (float*)take(2*B_*C_*4);                 // 4096
  float* sapms  = (float*)take(2*B_*C_*4);                 // 4096
  float* lrow   = (float*)take(2*B_*S_*4);                 // 16384 (plain store)
  float* ysum   = (float*)take(B_*C_*4);                   // 2048
  float* y2sum  = (float*)take(B_*C_*4);                   // 2048
  float* rsum   = (float*)take(2*B_*C_*4);                 // 4096
  float* rsum2  = (float*)take(2*B_*C_*4);                 // 4096
  float* tsum  = (float*)take(2*B_*T_*4);
  float* tsum2 = (float*)take(2*B_*T_*4);
  float* meanc = (float*)take(2*B_*C_*4);                  // [2][B][C]
  float* stdc  = (float*)take(2*B_*C_*4);
  float* beff  = (float*)take(B_*C_*4);
  float* bnsc  = (float*)take(C_*4);
  float* bnsh  = (float*)take(C_*4);
  float* sapl  = (float*)take(2*B_*S_*4);
  float* sapa  = (float*)take(2*B_*S_*4);

  dim3 blk(256);

  prep_k<<<6896, blk, 0, stream>>>((const float*)d_in[7], (const float*)d_in[4],
      (const float*)d_in[8], (const float*)d_in[5], (const float*)d_in[9],
      (const float*)d_in[6], WQb, conv2w, bn_g, bn_b, bn_m, bn_v, W2r, bnsc, bnsh,
      x1p, colsum);
  stats_k<<<dim3(T_/64, 2*B_), blk, 0, stream>>>(src, trg, tsum, tsum2, rsum, rsum2);
  transform_k<<<dim3(T_/32, C_/32, 2*B_), dim3(32,8), 0, stream>>>(src, trg,
      tsum, tsum2, rsum, rsum2, NSt, NSc, NTt, NTc, TTr);

  // QKV projections, both phases in one launch each.
  gemm_nt<0,4><<<dim3(C_/128, (B_*T_)/128, 4), blk, 0, stream>>>(NSc, WQb, QK4,
      C_, C_, C_, C_, BTC, (long long)C_*C_, BTC, 0, 1, 8, 1.f,
      nullptr, nullptr, nullptr, nullptr, nullptr, 0);
  gemm_nt<0,2><<<dim3(T_/64, C_/128, 8), blk, 0, stream>>>(WQb + (size_t)4*C_*C_, TTr, VT2,
      C_, C_, C_, T_, (long long)C_*C_, (long long)T_*C_, (long long)C_*T_, 0, 4, 4, 1.f,
      nullptr, nullptr, nullptr, nullptr, nullptr, 0);
  // P' = exp(Q @ K^T) bf16 (no max-sub: logits ~ N(0,1)); l computed by PV
  gemm_nt<5,4><<<dim3(T_/128, T_/128, 8), blk, 0, stream>>>(QK4, QK4 + 2*BTC, P2,
      C_, C_, C_, T_, (long long)T_*C_, (long long)T_*C_, (long long)S_*T_, 0, 1, 8, 1.f,
      nullptr, nullptr, nullptr, nullptr, nullptr, 0);
  // PV: ones-MFMA row sums l (stored to lrow by c==0 blocks), normalized
  // sum_s / sum_s^2 epilogue; XCD-pinned 1-D swizzle (z = id&7).
  gemm_nt<3,4><<<dim3(512, 1, 1), blk, 0, stream>>>(P2, VT2, lrow,
      T_, T_, T_, 0, (long long)S_*T_, (long long)C_*T_, S_, C_, 1, 8, 1.f,
      nullptr, nullptr, nullptr, msum, m2sum, 0);
  colsum_k<<<dim3(T_/256, S_/256, 8), blk, 0, stream>>>(P2, lrow, colsum);
  vv_fin_k<<<dim3(C_, 2*B_), blk, 0, stream>>>(colsum, VT2, msum, m2sum, meanc, stdc);

  // conv1 folded with adaptive-norm epilogues (TAN = phase 1, CAN = phase 0)
  weff_k<<<dim3(C_, B_), blk, 0, stream>>>(conv1w, conv1b,
      stdc + B_*C_, stdc, meanc + B_*C_, meanc, Weff, beff);
  gemm_nt<0,2><<<dim3(C_/64, T_/128, B_), blk, 0, stream>>>(NSc, Weff, x1p + C_,
      C_, C_, C_, C_, (long long)T_*C_, (long long)C_*C_, (long long)(T_+2)*C_, C_,
      1, 8, 1.f, nullptr, nullptr, beff, nullptr, nullptr, 0);
  // conv2 (k=3) as overlapping-row NT GEMM + BN+ReLU + fused row-stat sums
  gemm_nt<2,2><<<dim3(T_/64, C_/128, B_), blk, 0, stream>>>(W2r, x1p, y,
      3*C_, 3*C_, C_, T_, 0, (long long)(T_+2)*C_, (long long)C_*T_, 0,
      1, 8, 1.f, bnsc, bnsh, nullptr, ysum, y2sum, C_);

  sap_logit_k<<<dim3(S_/4, 2*B_), blk, 0, stream>>>(means, stds, msap_w, ssap_w,
      msap_b, ssap_b, sapl);
  softmax_row_k<<<2*B_, blk, 0, stream>>>(sapl, sapa);
  sap_wsum_k<<<dim3(C_/256, S_/256, 2*B_), blk, 0, stream>>>(means, stds, sapa, sapms);

  final_k<<<4096, blk, 0, stream>>>(y, ysum, y2sum, sapms, (float*)d_out);
}

// Round 6
// 455.412 us; speedup vs baseline: 1.1181x; 1.1181x over previous
//
#include <hip/hip_runtime.h>
#include <cstdint>
#include <cstddef>

#define B_ 4
#define C_ 512
#define T_ 2048
#define S_ 2048
#define EPSF 1e-5f

typedef __bf16 bf16;
typedef __attribute__((ext_vector_type(8))) __bf16 bf16x8;
typedef __attribute__((ext_vector_type(4))) float f32x4;

__device__ __forceinline__ bf16 f2b(float f){ return (bf16)f; }
__device__ __forceinline__ float b2f(bf16 h){ return (float)h; }

__device__ __forceinline__ void gl_lds16(const void* g, void* l){
  __builtin_amdgcn_global_load_lds((__attribute__((address_space(1))) void*)(g),
                                   (__attribute__((address_space(3))) void*)(l), 16, 0, 0);
}

__device__ __forceinline__ float wave_sum(float v){
#pragma unroll
  for (int o = 32; o; o >>= 1) v += __shfl_xor(v, o, 64);
  return v;
}
__device__ __forceinline__ float wave_max(float v){
#pragma unroll
  for (int o = 32; o; o >>= 1) v = fmaxf(v, __shfl_xor(v, o, 64));
  return v;
}

// ---------------------------------------------------------------------------
// NT GEMM: C[m,n] = sum_k A[m,k]*B[n,k], both operands k-contiguous (bf16),
// fp32 MFMA accum. Tile 128 x (TNW*32), BK=64, 256 threads (2x2 waves).
// z-batched: A offset (z/zdivA)*sA, B offset (z%zmodB)*sB, C offset z*sC.
// EPI 0: bf16 store (acc*scale + cbias[n])
// EPI 2: f32 store relu(acc*rs[m]+rsh[m]) + fused per-row sum/sum^2 atomics
// EPI 3: PV: ones-MFMA row sums l in-register; per-column sum/sum^2 over m of
//        acc/l[row] -> atomics into osum/osum2; c==0 blocks store l to Cout.
//        Uses XCD-pinned 1-D grid decode (z=id&7, c-block fastest).
// EPI 5: bf16 store exp(acc)   (unnormalized softmax numerator)
// ---------------------------------------------------------------------------
template<int EPI, int TNW>
__global__ void __launch_bounds__(256) gemm_nt(
    const bf16* __restrict__ A, const bf16* __restrict__ Bm, void* __restrict__ Cout,
    int K, int lda, int ldb, int ldc,
    long long sA, long long sB, long long sC, long long sCb,
    int zdivA, int zmodB, float scale,
    const float* __restrict__ rs, const float* __restrict__ rsh,
    const float* __restrict__ cbias,
    float* __restrict__ osum, float* __restrict__ osum2, long long sRs)
{
  constexpr int TN = TNW*32;
  __shared__ alignas(16) bf16 lA[128*64];
  __shared__ alignas(16) bf16 lB[TN*64];
  __shared__ float l_sh[128];
  const int tid = threadIdx.x;
  int z, m0, n0;
  if (EPI == 3) {         // XCD-pinned swizzle: z = id&7, c-block fastest
    const int id = blockIdx.x;
    z = id & 7;
    const int r = id >> 3;
    n0 = (r & 3) * TN;    // C_/TN must be 4 (TNW=4)
    m0 = (r >> 2) * 128;
  } else {
    z = blockIdx.z; m0 = blockIdx.y*128; n0 = blockIdx.x*TN;
  }
  const bf16* Ab = A + (long long)(z / zdivA) * sA;
  const bf16* Bb = Bm + (long long)(z % zmodB) * sB;
  const int lane = tid & 63, wvi = tid >> 6;
  const int wm = wvi >> 1, wn = wvi & 1;

  f32x4 acc[4][TNW] = {};
  f32x4 accL[4] = {};                       // EPI==3: row sums via ones-MFMA
  bf16x8 vone;
#pragma unroll
  for (int j = 0; j < 8; ++j) vone[j] = f2b(1.f);

  // loader: thread stages one 16B chunk/iter; XOR-swizzle k-chunk by (row&7)
  const int lrow = tid >> 3;
  const int lcol = ((tid ^ lrow) & 7) * 8;
  const bf16* pa = Ab + (long long)(m0 + lrow)*lda + lcol;
  const bf16* pb = Bb + (long long)(n0 + lrow)*ldb + lcol;
  char* sa = (char*)lA + tid*16;
  char* sb = (char*)lB + tid*16;

  for (int k0 = 0; k0 < K; k0 += 64) {
#pragma unroll
    for (int it = 0; it < 4; ++it)
      gl_lds16(pa + (long long)it*32*lda + k0, sa + it*4096);
#pragma unroll
    for (int it = 0; it < TNW; ++it)
      gl_lds16(pb + (long long)it*32*ldb + k0, sb + it*4096);
    __syncthreads();
#pragma unroll
    for (int ks = 0; ks < 2; ++ks) {
      const int kq = ks*4 + (lane >> 4);
      bf16x8 af[4], bfr[TNW];
#pragma unroll
      for (int mt = 0; mt < 4; ++mt) {
        int r = wm*64 + mt*16 + (lane & 15);
        af[mt] = *(const bf16x8*)&lA[r*64 + ((kq ^ (r & 7))*8)];
      }
#pragma unroll
      for (int nt = 0; nt < TNW; ++nt) {
        int r = wn*(TNW*16) + nt*16 + (lane & 15);
        bfr[nt] = *(const bf16x8*)&lB[r*64 + ((kq ^ (r & 7))*8)];
      }
#pragma unroll
      for (int mt = 0; mt < 4; ++mt)
#pragma unroll
        for (int nt = 0; nt < TNW; ++nt)
          acc[mt][nt] = __builtin_amdgcn_mfma_f32_16x16x32_bf16(af[mt], bfr[nt], acc[mt][nt], 0, 0, 0);
      if (EPI == 3 && wn == 0) {
#pragma unroll
        for (int mt = 0; mt < 4; ++mt)
          accL[mt] = __builtin_amdgcn_mfma_f32_16x16x32_bf16(af[mt], vone, accL[mt], 0, 0, 0);
      }
    }
    __syncthreads();
  }

  if (EPI == 3) {
    // publish l (row sums) to LDS, then normalize-and-reduce columns.
    if (wn == 0 && (lane & 15) == 0) {
#pragma unroll
      for (int mt = 0; mt < 4; ++mt)
#pragma unroll
        for (int i = 0; i < 4; ++i)
          l_sh[wm*64 + mt*16 + (lane >> 4)*4 + i] = accL[mt][i];
    }
    __syncthreads();
    if (n0 == 0 && tid < 128)
      ((float*)Cout)[(long long)z*sC + m0 + tid] = l_sh[tid];
    float linv[4][4];
#pragma unroll
    for (int mt = 0; mt < 4; ++mt)
#pragma unroll
      for (int i = 0; i < 4; ++i)
        linv[mt][i] = 1.f / l_sh[wm*64 + mt*16 + (lane >> 4)*4 + i];
    float* red1 = (float*)lA;                 // [4][TNW][16] aliased scratch
    float* red2 = red1 + 4*TNW*16;
    float s1[TNW], s2[TNW];
#pragma unroll
    for (int nt = 0; nt < TNW; ++nt) {
      s1[nt] = 0.f; s2[nt] = 0.f;
#pragma unroll
      for (int mt = 0; mt < 4; ++mt)
#pragma unroll
        for (int i = 0; i < 4; ++i) {
          float v = acc[mt][nt][i] * linv[mt][i];
          s1[nt] += v; s2[nt] += v*v;
        }
      s1[nt] += __shfl_xor(s1[nt], 16, 64);
      s1[nt] += __shfl_xor(s1[nt], 32, 64);
      s2[nt] += __shfl_xor(s2[nt], 16, 64);
      s2[nt] += __shfl_xor(s2[nt], 32, 64);
    }
    if (lane < 16) {
#pragma unroll
      for (int nt = 0; nt < TNW; ++nt) {
        red1[(wvi*TNW + nt)*16 + lane] = s1[nt];
        red2[(wvi*TNW + nt)*16 + lane] = s2[nt];
      }
    }
    __syncthreads();
    if (tid < 2*TN) {
      const int which = tid >= TN;
      const int col = tid - which*TN;
      const int wn2 = col / (TNW*16), rem = col % (TNW*16);
      const float* rr = which ? red2 : red1;
      float v = rr[wn2*(TNW*16) + rem] + rr[(2+wn2)*(TNW*16) + rem];
      float* dst = which ? osum2 : osum;
      atomicAdd(&dst[sCb*z + n0 + col], v);
    }
    return;
  }

  const int cr = (lane >> 4)*4, cc = lane & 15;
#pragma unroll
  for (int mt = 0; mt < 4; ++mt) {
#pragma unroll
    for (int i = 0; i < 4; ++i) {
      const int mm = m0 + wm*64 + mt*16 + cr + i;
      float rsum = 0.f, rsum2 = 0.f;
#pragma unroll
      for (int nt = 0; nt < TNW; ++nt) {
        const int nn = n0 + wn*(TNW*16) + nt*16 + cc;
        float v = acc[mt][nt][i];
        const long long co = sC*z + (long long)mm*ldc + nn;
        if (EPI == 0) {
          v *= scale;
          if (cbias) v += cbias[sCb*z + nn];
          ((bf16*)Cout)[co] = f2b(v);
        } else if (EPI == 2) {
          v = fmaxf(v*rs[mm] + rsh[mm], 0.f);
          ((float*)Cout)[co] = v;
          rsum += v; rsum2 += v*v;
        } else if (EPI == 5) {
          ((bf16*)Cout)[co] = f2b(__expf(v));
        }
      }
      if (EPI == 2) {
        rsum += __shfl_xor(rsum, 1, 64); rsum += __shfl_xor(rsum, 2, 64);
        rsum += __shfl_xor(rsum, 4, 64); rsum += __shfl_xor(rsum, 8, 64);
        rsum2 += __shfl_xor(rsum2, 1, 64); rsum2 += __shfl_xor(rsum2, 2, 64);
        rsum2 += __shfl_xor(rsum2, 4, 64); rsum2 += __shfl_xor(rsum2, 8, 64);
        if (cc == 0) {
          atomicAdd(&osum[(long long)z*sRs + mm], rsum);
          atomicAdd(&osum2[(long long)z*sRs + mm], rsum2);
        }
      }
    }
  }
}

// ---- per-row (contiguous, len 2048) mean/std, ddof=1; rows<n1 from X1 ------
__global__ void __launch_bounds__(256) row_stats_k(const float* __restrict__ X1,
    const float* __restrict__ X2, float* __restrict__ Mo, float* __restrict__ So, int n1)
{
  __shared__ float r1[4], r2[4];
  const int row = blockIdx.x;
  const float* x = (row < n1) ? X1 + (long long)row*T_ : X2 + (long long)(row-n1)*T_;
  float s1 = 0.f, s2 = 0.f;
  for (int i = threadIdx.x; i < T_; i += 256){ float v = x[i]; s1 += v; s2 += v*v; }
  s1 = wave_sum(s1); s2 = wave_sum(s2);
  const int lane = threadIdx.x & 63, w = threadIdx.x >> 6;
  if (!lane){ r1[w] = s1; r2[w] = s2; }
  __syncthreads();
  if (threadIdx.x == 0){
    s1 = r1[0]+r1[1]+r1[2]+r1[3];
    s2 = r2[0]+r2[1]+r2[2]+r2[3];
    float m = s1 * (1.f/T_);
    float var = (s2 - s1*m) * (1.f/(T_-1));
    Mo[row] = m; So[row] = sqrtf(fmaxf(var, 0.f));
  }
}

// ---- per-(b,t) mean/std over channels, src (z<B) / trg (z>=B), ddof=1 ------
__global__ void __launch_bounds__(256) col_stats_k(const float* __restrict__ src,
    const float* __restrict__ trg, float* __restrict__ Mo, float* __restrict__ So)
{
  __shared__ float r1[4][64], r2[4][64];
  const int z = blockIdx.y, t0 = blockIdx.x*64;
  const float* X = (z < B_) ? src : trg;
  const int b = z & (B_-1);
  const int tl = threadIdx.x & 63, cg = threadIdx.x >> 6;
  float s1 = 0.f, s2 = 0.f;
  for (int c = cg; c < C_; c += 4) {
    float v = X[((long long)b*C_ + c)*T_ + t0 + tl];
    s1 += v; s2 += v*v;
  }
  r1[cg][tl] = s1; r2[cg][tl] = s2;
  __syncthreads();
  if (cg == 0) {
    s1 = r1[0][tl]+r1[1][tl]+r1[2][tl]+r1[3][tl];
    s2 = r2[0][tl]+r2[1][tl]+r2[2][tl]+r2[3][tl];
    float m = s1 * (1.f/C_);
    float var = (s2 - s1*m) * (1.f/(C_-1));
    Mo[z*T_ + t0 + tl] = m;
    So[z*T_ + t0 + tl] = sqrtf(fmaxf(var, 0.f));
  }
}

// ---- transpose [C,T]->[T,C] + write tinorm & inorm bf16 (src & trg) --------
__global__ void __launch_bounds__(256) transform_k(const float* __restrict__ src,
    const float* __restrict__ trg,
    const float* __restrict__ tnm, const float* __restrict__ tns,
    const float* __restrict__ inm, const float* __restrict__ ins,
    bf16* __restrict__ NSt, bf16* __restrict__ NSc,
    bf16* __restrict__ NTt, bf16* __restrict__ NTc, bf16* __restrict__ TTr)
{
  __shared__ float tile[32][33];
  const int z = blockIdx.z, t0 = blockIdx.x*32, c0 = blockIdx.y*32;
  const int is_t = z >= B_, b = z & (B_-1);
  const float* X = is_t ? trg : src;
  const int tx = threadIdx.x, ty = threadIdx.y;
#pragma unroll
  for (int r = 0; r < 4; ++r) {
    int ci = ty + r*8;
    tile[ci][tx] = X[((long long)b*C_ + c0 + ci)*T_ + t0 + tx];
  }
  __syncthreads();
#pragma unroll
  for (int r = 0; r < 4; ++r) {
    int tj = ty + r*8, ci = tx;
    float v = tile[ci][tj];
    int gt = t0 + tj, gc = c0 + ci;
    float a = (v - tnm[z*T_ + gt]) / (tns[z*T_ + gt] + EPSF);
    float d = (v - inm[z*C_ + gc]) / (ins[z*C_ + gc] + EPSF);
    long long o = ((long long)b*T_ + gt)*C_ + gc;
    if (is_t) { NTt[o] = f2b(a); NTc[o] = f2b(d); TTr[o] = f2b(v); }
    else      { NSt[o] = f2b(a); NSc[o] = f2b(d); }
  }
}

// ---- fp32 row softmax (SAP) ------------------------------------------------
__global__ void __launch_bounds__(256) softmax_row_k(const float* __restrict__ X, float* __restrict__ O)
{
  __shared__ float red[4];
  const long long row = blockIdx.x;
  const float* x = X + row*T_ + threadIdx.x*8;
  float v[8];
  f32x4 a0 = *(const f32x4*)x;
  f32x4 a1 = *(const f32x4*)(x + 4);
#pragma unroll
  for (int j = 0; j < 4; ++j){ v[j] = a0[j]; v[4+j] = a1[j]; }
  float m = -3.4e38f;
#pragma unroll
  for (int j = 0; j < 8; ++j) m = fmaxf(m, v[j]);
  m = wave_max(m);
  const int lane = threadIdx.x & 63, w = threadIdx.x >> 6;
  if (!lane) red[w] = m;
  __syncthreads();
  m = fmaxf(fmaxf(red[0], red[1]), fmaxf(red[2], red[3]));
  __syncthreads();
  float s = 0.f;
#pragma unroll
  for (int j = 0; j < 8; ++j){ v[j] = __expf(v[j] - m); s += v[j]; }
  s = wave_sum(s);
  if (!lane) red[w] = s;
  __syncthreads();
  s = red[0]+red[1]+red[2]+red[3];
  const float inv = 1.f/s;
  float* o = O + row*T_ + threadIdx.x*8;
#pragma unroll
  for (int j = 0; j < 8; ++j) o[j] = v[j]*inv;
}

// ---- normalized column sums of P' over s (chunked, atomic), z in [0,2B) ----
__global__ void __launch_bounds__(256) colsum_k(const bf16* __restrict__ P,
    const float* __restrict__ l, float* __restrict__ cs)
{
  __shared__ float linv[256];
  const int t = blockIdx.x*256 + threadIdx.x;
  const int z = blockIdx.z;
  const long long s0 = (long long)blockIdx.y*256;
  linv[threadIdx.x] = 1.f / l[(long long)z*S_ + s0 + threadIdx.x];
  __syncthreads();
  const bf16* p = P + ((long long)z*S_ + s0)*T_ + t;
  float a = 0.f;
  for (int s = 0; s < 256; ++s) a += b2f(p[(long long)s*T_]) * linv[s];
  atomicAdd(&cs[z*T_ + t], a);
}

// ---- vv-GEMV + finalize mean_c / std_c, z in [0,2B) ------------------------
__global__ void __launch_bounds__(256) vv_fin_k(const float* __restrict__ cs,
    const bf16* __restrict__ VT, const float* __restrict__ msum,
    const float* __restrict__ m2sum, float* __restrict__ meanc, float* __restrict__ stdc)
{
  __shared__ float r1[4];
  const int c = blockIdx.x, z = blockIdx.y;
  const bf16* vr = VT + ((long long)z*C_ + c)*T_;
  const float* w = cs + z*T_;
  float a = 0.f;
  for (int t = threadIdx.x; t < T_; t += 256){ float v = b2f(vr[t]); a += w[t]*v*v; }
  a = wave_sum(a);
  const int lane = threadIdx.x & 63, wq = threadIdx.x >> 6;
  if (!lane) r1[wq] = a;
  __syncthreads();
  if (threadIdx.x == 0){
    a = r1[0]+r1[1]+r1[2]+r1[3];
    const int idx = z*C_ + c;
    meanc[idx] = msum[idx] * (1.f/S_);
    float var = (a - m2sum[idx]) * (1.f/S_);
    stdc[idx] = sqrtf(fmaxf(var, 0.f));
  }
}

// ---- fold adaptive-norm epilogue + concat into conv1 weights ---------------
__global__ void __launch_bounds__(256) weff_k(const float* __restrict__ w1,
    const float* __restrict__ b1, const float* __restrict__ sdt, const float* __restrict__ sdc,
    const float* __restrict__ mct, const float* __restrict__ mcc,
    bf16* __restrict__ Weff, float* __restrict__ beff)
{
  __shared__ float r1[4];
  const int o = blockIdx.x, b = blockIdx.y;
  float accb = 0.f;
  for (int c = threadIdx.x; c < C_; c += 256) {
    float wa = w1[o*2*C_ + c], wb = w1[o*2*C_ + C_ + c];
    Weff[((long long)(b*C_ + o))*C_ + c] = f2b(wa*sdt[b*C_+c] + wb*sdc[b*C_+c]);
    accb += wa*mct[b*C_+c] + wb*mcc[b*C_+c];
  }
  accb = wave_sum(accb);
  const int lane = threadIdx.x & 63, w = threadIdx.x >> 6;
  if (!lane) r1[w] = accb;
  __syncthreads();
  if (threadIdx.x == 0) beff[b*C_ + o] = b1[o] + r1[0]+r1[1]+r1[2]+r1[3];
}

// ---- merged prep: cast6 | w2r+BN | x1p pad | zero accumulators -------------
__global__ void __launch_bounds__(256) prep_k(
    const float* __restrict__ a0, const float* __restrict__ a1,
    const float* __restrict__ a2, const float* __restrict__ a3,
    const float* __restrict__ a4, const float* __restrict__ a5,
    bf16* __restrict__ WQb,
    const float* __restrict__ w2, const float* __restrict__ g,
    const float* __restrict__ be, const float* __restrict__ mu,
    const float* __restrict__ va, bf16* __restrict__ W2r,
    float* __restrict__ bnsc, float* __restrict__ bnsh,
    bf16* __restrict__ x1p, float* __restrict__ zbase)
{
  const int bid = blockIdx.x, tid = threadIdx.x;
  if (bid < 6144) {                       // cast 6 proj weights (qsc folded)
    const int i = bid*256 + tid;
    const int slot = i >> 18;
    const float* srcs[6] = {a0,a1,a2,a3,a4,a5};
    const float sc = (slot < 2) ? 0.044194173824159216f : 1.f;
    WQb[i] = f2b(srcs[slot][i & 262143] * sc);
  } else if (bid < 6656) {                // conv2 weight reorder + BN consts
    const int o = bid - 6144;
    for (int c = tid; c < C_; c += 256)
#pragma unroll
      for (int dt = 0; dt < 3; ++dt)
        W2r[(long long)o*3*C_ + dt*C_ + c] = f2b(w2[((long long)o*C_ + c)*3 + dt]);
    if (tid == 0) {
      float s = g[o] * rsqrtf(va[o] + EPSF);
      bnsc[o] = s;
      bnsh[o] = be[o] - mu[o]*s;
    }
  } else if (bid < 6672) {                // zero-pad halo rows of x1p
    const int i = (bid - 6656)*256 + tid;
    const int b = i >> 10, rem = i & 1023;
    const long long row = (rem >> 9) ? (T_+1) : 0;
    const int c = rem & (C_-1);
    x1p[((long long)b*(T_+2) + row)*C_ + c] = f2b(0.f);
  } else {                                // zero the accumulator region
    zbase[(bid - 6672)*256 + tid] = 0.f;
  }
}

// ---- SAP: logits (means for z<B, stds for z>=B) ----------------------------
__global__ void __launch_bounds__(256) sap_logit_k(const float* __restrict__ means,
    const float* __restrict__ stds, const float* __restrict__ mw, const float* __restrict__ sw,
    const float* __restrict__ mb, const float* __restrict__ sb, float* __restrict__ out)
{
  const int n = blockIdx.x*4 + (threadIdx.x >> 6);
  const int z = blockIdx.y;
  const int sel = z >= B_, b = z & (B_-1);
  const float* x = sel ? stds : means;
  const float* w = sel ? sw : mw;
  const int lane = threadIdx.x & 63;
  const float* p = x + ((long long)b*S_ + n)*C_;
  float a = 0.f;
  for (int c = lane; c < C_; c += 64) a += p[c]*w[c];
  a = wave_sum(a);
  if (!lane) out[z*S_ + n] = a + (sel ? sb[0] : mb[0]);
}

// ---- SAP: weighted sum over n (chunked, atomic), z in [0,2B) ---------------
__global__ void __launch_bounds__(256) sap_wsum_k(const float* __restrict__ means,
    const float* __restrict__ stds, const float* __restrict__ a, float* __restrict__ out)
{
  const int c = blockIdx.x*256 + threadIdx.x;
  const int z = blockIdx.z;
  const int sel = z >= B_, b = z & (B_-1);
  const float* x = sel ? stds : means;
  const long long n0 = (long long)blockIdx.y*256;
  const float* p = x + ((long long)b*S_ + n0)*C_ + c;
  const float* aw = a + z*S_ + n0;
  float acc = 0.f;
  for (int n = 0; n < 256; ++n) acc += p[(long long)n*C_] * aw[n];
  atomicAdd(&out[z*C_ + c], acc);
}

// ---- final: inorm(y)*sap_std + sap_mean, stats from raw sums ---------------
__global__ void __launch_bounds__(256) final_k(const float* __restrict__ y,
    const float* __restrict__ ysum, const float* __restrict__ y2sum,
    const float* __restrict__ sapms, float* __restrict__ out)
{
  const long long i = (long long)(blockIdx.x*256 + threadIdx.x) * 4;
  const long long r = i >> 11;
  const float s1 = ysum[r], s2 = y2sum[r];
  const float m = s1 * (1.f/T_);
  const float var = (s2 - s1*m) * (1.f/(T_-1));
  const float inv = 1.f/(sqrtf(fmaxf(var, 0.f)) + EPSF);
  const float mn = sapms[r], sd = sapms[B_*C_ + r];
  const f32x4 v = *(const f32x4*)(y + i);
  f32x4 o;
#pragma unroll
  for (int j = 0; j < 4; ++j) o[j] = (v[j] - m)*inv*sd + mn;
  *(f32x4*)(out + i) = o;
}

// ---------------------------------------------------------------------------
extern "C" void kernel_launch(void* const* d_in, const int* in_sizes, int n_in,
                              void* d_out, int out_size, void* d_ws, size_t ws_size,
                              hipStream_t stream)
{
  (void)in_sizes; (void)n_in; (void)out_size; (void)ws_size;
  const float* src    = (const float*)d_in[0];
  const float* trg    = (const float*)d_in[1];
  const float* means  = (const float*)d_in[2];
  const float* stds   = (const float*)d_in[3];
  const float* conv1w = (const float*)d_in[10];
  const float* conv1b = (const float*)d_in[11];
  const float* conv2w = (const float*)d_in[12];
  const float* bn_g   = (const float*)d_in[13];
  const float* bn_b   = (const float*)d_in[14];
  const float* bn_m   = (const float*)d_in[15];
  const float* bn_v   = (const float*)d_in[16];
  const float* msap_w = (const float*)d_in[17];
  const float* msap_b = (const float*)d_in[18];
  const float* ssap_w = (const float*)d_in[19];
  const float* ssap_b = (const float*)d_in[20];

  const long long BTC = (long long)B_*T_*C_;   // 4194304 elems

  char* p = (char*)d_ws;
  auto take = [&](size_t n)->char*{ char* r = p; p += (n + 255) & ~(size_t)255; return r; };

  // Phase convention: p=0 -> CAN (inorm), p=1 -> TAN (tinorm); z = p*B + b.
  bf16* NSc = (bf16*)take(BTC*2);                          // 8 MB
  bf16* P2  = (bf16*)take((size_t)2*B_*S_*T_*2);           // 64 MB (exp logits)
  bf16* NSt = P2;                                          // aliases (dead
  bf16* NTc = P2 + BTC;                                    //  before QK gemm
  bf16* NTt = P2 + 2*BTC;                                  //  writes P2)
  bf16* TTr = P2 + 3*BTC;
  bf16* QK4 = (bf16*)take((size_t)4*BTC*2);                // 32 MB [Qc,Qt,Kc,Kt]
  bf16* VT2 = (bf16*)take((size_t)2*BTC*2);                // 16 MB [2][B][C][T]
  bf16* WQb = (bf16*)take((size_t)6*C_*C_*2);
  bf16* Weff= (bf16*)take((size_t)B_*C_*C_*2);
  bf16* W2r = (bf16*)take((size_t)C_*3*C_*2);
  bf16* x1p = (bf16*)take((size_t)B_*(T_+2)*C_*2);
  float* y  = (float*)take((size_t)B_*C_*T_*4);            // 16 MB
  // contiguous zero region (prep_k part 4): 49152 floats = 192 blocks
  float* colsum = (float*)take(2*B_*T_*4);                 // 16384 f
  float* msum   = (float*)take(2*B_*C_*4);                 // 4096
  float* m2sum  = (float*)take(2*B_*C_*4);                 // 4096
  float* sapms  = (float*)take(2*B_*C_*4);                 // 4096
  float* lrow   = (float*)take(2*B_*S_*4);                 // 16384 (plain store)
  float* ysum   = (float*)take(B_*C_*4);                   // 2048
  float* y2sum  = (float*)take(B_*C_*4);                   // 2048
  float* tnm = (float*)take(2*B_*T_*4);
  float* tns = (float*)take(2*B_*T_*4);
  float* inm = (float*)take(2*B_*C_*4);
  float* ins = (float*)take(2*B_*C_*4);
  float* meanc = (float*)take(2*B_*C_*4);                  // [2][B][C]
  float* stdc  = (float*)take(2*B_*C_*4);
  float* beff  = (float*)take(B_*C_*4);
  float* bnsc  = (float*)take(C_*4);
  float* bnsh  = (float*)take(C_*4);
  float* sapl  = (float*)take(2*B_*S_*4);
  float* sapa  = (float*)take(2*B_*S_*4);

  dim3 blk(256);

  prep_k<<<6864, blk, 0, stream>>>((const float*)d_in[7], (const float*)d_in[4],
      (const float*)d_in[8], (const float*)d_in[5], (const float*)d_in[9],
      (const float*)d_in[6], WQb, conv2w, bn_g, bn_b, bn_m, bn_v, W2r, bnsc, bnsh,
      x1p, colsum);
  row_stats_k<<<2*B_*C_, blk, 0, stream>>>(src, trg, inm, ins, B_*C_);
  col_stats_k<<<dim3(T_/64, 2*B_), blk, 0, stream>>>(src, trg, tnm, tns);
  transform_k<<<dim3(T_/32, C_/32, 2*B_), dim3(32,8), 0, stream>>>(src, trg,
      tnm, tns, inm, ins, NSt, NSc, NTt, NTc, TTr);

  // QKV projections, both phases in one launch each.
  gemm_nt<0,4><<<dim3(C_/128, (B_*T_)/128, 4), blk, 0, stream>>>(NSc, WQb, QK4,
      C_, C_, C_, C_, BTC, (long long)C_*C_, BTC, 0, 1, 8, 1.f,
      nullptr, nullptr, nullptr, nullptr, nullptr, 0);
  gemm_nt<0,2><<<dim3(T_/64, C_/128, 8), blk, 0, stream>>>(WQb + (size_t)4*C_*C_, TTr, VT2,
      C_, C_, C_, T_, (long long)C_*C_, (long long)T_*C_, (long long)C_*T_, 0, 4, 4, 1.f,
      nullptr, nullptr, nullptr, nullptr, nullptr, 0);
  // P' = exp(Q @ K^T) bf16 (no max-sub: logits ~ N(0,1)); l computed by PV
  gemm_nt<5,4><<<dim3(T_/128, T_/128, 8), blk, 0, stream>>>(QK4, QK4 + 2*BTC, P2,
      C_, C_, C_, T_, (long long)T_*C_, (long long)T_*C_, (long long)S_*T_, 0, 1, 8, 1.f,
      nullptr, nullptr, nullptr, nullptr, nullptr, 0);
  // PV: ones-MFMA row sums l (stored to lrow by c==0 blocks), normalized
  // sum_s / sum_s^2 epilogue; XCD-pinned 1-D swizzle (z = id&7).
  gemm_nt<3,4><<<dim3(512, 1, 1), blk, 0, stream>>>(P2, VT2, lrow,
      T_, T_, T_, 0, (long long)S_*T_, (long long)C_*T_, S_, C_, 1, 8, 1.f,
      nullptr, nullptr, nullptr, msum, m2sum, 0);
  colsum_k<<<dim3(T_/256, S_/256, 8), blk, 0, stream>>>(P2, lrow, colsum);
  vv_fin_k<<<dim3(C_, 2*B_), blk, 0, stream>>>(colsum, VT2, msum, m2sum, meanc, stdc);

  // conv1 folded with adaptive-norm epilogues (TAN = phase 1, CAN = phase 0)
  weff_k<<<dim3(C_, B_), blk, 0, stream>>>(conv1w, conv1b,
      stdc + B_*C_, stdc, meanc + B_*C_, meanc, Weff, beff);
  gemm_nt<0,2><<<dim3(C_/64, T_/128, B_), blk, 0, stream>>>(NSc, Weff, x1p + C_,
      C_, C_, C_, C_, (long long)T_*C_, (long long)C_*C_, (long long)(T_+2)*C_, C_,
      1, 8, 1.f, nullptr, nullptr, beff, nullptr, nullptr, 0);
  // conv2 (k=3) as overlapping-row NT GEMM + BN+ReLU + fused row-stat sums
  gemm_nt<2,2><<<dim3(T_/64, C_/128, B_), blk, 0, stream>>>(W2r, x1p, y,
      3*C_, 3*C_, C_, T_, 0, (long long)(T_+2)*C_, (long long)C_*T_, 0,
      1, 8, 1.f, bnsc, bnsh, nullptr, ysum, y2sum, C_);

  sap_logit_k<<<dim3(S_/4, 2*B_), blk, 0, stream>>>(means, stds, msap_w, ssap_w,
      msap_b, ssap_b, sapl);
  softmax_row_k<<<2*B_, blk, 0, stream>>>(sapl, sapa);
  sap_wsum_k<<<dim3(C_/256, S_/256, 2*B_), blk, 0, stream>>>(means, stds, sapa, sapms);

  final_k<<<4096, blk, 0, stream>>>(y, ysum, y2sum, sapms, (float*)d_out);
}